// Round 4
// baseline (52.595 us; speedup 1.0000x reference)
//
#include <hip/hip_runtime.h>

#define N 8192
#define BLOCKT 128
#define ITILE 256                  // 2 i-points per thread
#define NB (N / ITILE)             // 32
#define NTRI (NB * (NB + 1) / 2)   // 528 triangular tiles
#define JSPLIT 4
#define JSUB (ITILE / JSPLIT)      // 64 j-points per block
#define NPART (NTRI * JSPLIT)      // 2112 partials

// 9-image Coulomb sum for one pair (dx, dy), shifts {-10,0,10}^2.
// (dx±10)^2 = fma(±20, dx, dx^2+100)
__device__ __forceinline__ float pair9(float dx, float dy) {
    float x0 = dx * dx, y0 = dy * dy;
    float tx = x0 + 100.0f, ty = y0 + 100.0f;
    float xm = fmaf(20.0f, dx, tx),  xp = fmaf(-20.0f, dx, tx);
    float ym = fmaf(20.0f, dy, ty),  yp = fmaf(-20.0f, dy, ty);
    return __builtin_amdgcn_rsqf(x0 + y0)
         + __builtin_amdgcn_rsqf(x0 + ym)
         + __builtin_amdgcn_rsqf(x0 + yp)
         + __builtin_amdgcn_rsqf(xm + y0)
         + __builtin_amdgcn_rsqf(xm + ym)
         + __builtin_amdgcn_rsqf(xm + yp)
         + __builtin_amdgcn_rsqf(xp + y0)
         + __builtin_amdgcn_rsqf(xp + ym)
         + __builtin_amdgcn_rsqf(xp + yp);
}

// Same but with the diagonal (i==j) fully masked (all 9 shifts), center d2 made safe.
__device__ __forceinline__ float pair9_masked(float dx, float dy, bool diag) {
    float x0 = dx * dx, y0 = dy * dy;
    float tx = x0 + 100.0f, ty = y0 + 100.0f;
    float xm = fmaf(20.0f, dx, tx),  xp = fmaf(-20.0f, dx, tx);
    float ym = fmaf(20.0f, dy, ty),  yp = fmaf(-20.0f, dy, ty);
    float d2c = diag ? 1.0f : (x0 + y0);
    float s = __builtin_amdgcn_rsqf(d2c)
            + __builtin_amdgcn_rsqf(x0 + ym)
            + __builtin_amdgcn_rsqf(x0 + yp)
            + __builtin_amdgcn_rsqf(xm + y0)
            + __builtin_amdgcn_rsqf(xm + ym)
            + __builtin_amdgcn_rsqf(xm + yp)
            + __builtin_amdgcn_rsqf(xp + y0)
            + __builtin_amdgcn_rsqf(xp + ym)
            + __builtin_amdgcn_rsqf(xp + yp);
    return diag ? 0.0f : s;
}

// Triangular 256x256 tiles, 2 i-points per thread, j-split by 4 for parallelism.
__global__ __launch_bounds__(BLOCKT) void pe_kernel(const float* __restrict__ xy,
                                                    float* __restrict__ partial) {
    __shared__ float2 sj[JSUB];
    const int t = threadIdx.x;

    // decode triangular index (scalar loop, <=32 SALU iters once per block)
    int rem = blockIdx.x;
    int ib = 0;
    while (rem >= NB - ib) { rem -= NB - ib; ++ib; }
    const int jb = ib + rem;

    const int i0 = ib * ITILE + t;
    const int i1 = i0 + BLOCKT;
    const float2 p0 = ((const float2*)xy)[i0];
    const float2 p1 = ((const float2*)xy)[i1];

    const int j0 = jb * ITILE + blockIdx.y * JSUB;
    if (t < JSUB) sj[t] = ((const float2*)xy)[j0 + t];
    __syncthreads();

    float acc0 = 0.0f, acc1 = 0.0f;

    if (ib == jb) {
#pragma unroll 4
        for (int jj = 0; jj < JSUB; ++jj) {
            float2 pj = sj[jj];
            int j = j0 + jj;
            acc0 += pair9_masked(p0.x - pj.x, p0.y - pj.y, i0 == j);
            acc1 += pair9_masked(p1.x - pj.x, p1.y - pj.y, i1 == j);
        }
    } else {
#pragma unroll 4
        for (int jj = 0; jj < JSUB; ++jj) {
            float2 pj = sj[jj];
            acc0 += pair9(p0.x - pj.x, p0.y - pj.y);
            acc1 += pair9(p1.x - pj.x, p1.y - pj.y);
        }
        // weight 2: mirrored (j,i) tile (shift set is self-negating)
        acc0 += acc0;
        acc1 += acc1;
    }

    float acc = acc0 + acc1;

    // deterministic block tree reduction
    __shared__ float red[BLOCKT];
    red[t] = acc;
    __syncthreads();
    for (int s = BLOCKT / 2; s > 0; s >>= 1) {
        if (t < s) red[t] += red[t + s];
        __syncthreads();
    }
    if (t == 0) partial[blockIdx.y * NTRI + blockIdx.x] = red[0];
}

// Finisher: reduce NPART block partials + kinetic energy, write scalar.
__global__ __launch_bounds__(1024) void finish_kernel(const float* __restrict__ partial,
                                                      const float* __restrict__ pxy,
                                                      float* __restrict__ out) {
    const int t = threadIdx.x;
    float acc = 0.0f;
    for (int k = t; k < NPART; k += 1024) acc += partial[k];
    for (int k = t; k < 2 * N; k += 1024) {   // KE = sum p^2 / 2
        float p = pxy[k];
        acc += 0.5f * p * p;
    }
    __shared__ float red[1024];
    red[t] = acc;
    __syncthreads();
    for (int s = 512; s > 0; s >>= 1) {
        if (t < s) red[t] += red[t + s];
        __syncthreads();
    }
    if (t == 0) out[0] = red[0];
}

extern "C" void kernel_launch(void* const* d_in, const int* in_sizes, int n_in,
                              void* d_out, int out_size, void* d_ws, size_t ws_size,
                              hipStream_t stream) {
    const float* xy  = (const float*)d_in[0];
    const float* pxy = (const float*)d_in[1];
    float* out       = (float*)d_out;
    float* partial   = (float*)d_ws;   // NPART floats = 8448 B

    dim3 grid(NTRI, JSPLIT);
    pe_kernel<<<grid, BLOCKT, 0, stream>>>(xy, partial);
    finish_kernel<<<1, 1024, 0, stream>>>(partial, pxy, out);
}

// Round 5
// 47.697 us; speedup vs baseline: 1.1027x; 1.1027x over previous
//
#include <hip/hip_runtime.h>

#define N 8192
#define BLOCK 256
#define ITILE 256                  // 1 i-point per thread, 256-wide i-tile
#define NB (N / ITILE)             // 32
#define NTRI (NB * (NB + 1) / 2)   // 528 triangular tiles
#define JSPLIT 4
#define JSUB (ITILE / JSPLIT)      // 64 j-points per block
#define NPART (NTRI * JSPLIT)      // 2112 partials

#define RSQ __builtin_amdgcn_rsqf

// 9-image Coulomb sum, shifts {-10,0,10}^2; (dx±10)^2 = fma(±20, dx, dx^2+100).
// Tree-structured sum (depth 4) to shorten the dependence chain after the rsq's.
__device__ __forceinline__ float pair9(float dx, float dy) {
    float x0 = dx * dx, y0 = dy * dy;
    float tx = x0 + 100.0f, ty = y0 + 100.0f;
    float xm = fmaf(20.0f, dx, tx),  xp = fmaf(-20.0f, dx, tx);
    float ym = fmaf(20.0f, dy, ty),  yp = fmaf(-20.0f, dy, ty);
    float r0 = RSQ(x0 + y0), r1 = RSQ(x0 + ym), r2 = RSQ(x0 + yp);
    float r3 = RSQ(xm + y0), r4 = RSQ(xm + ym), r5 = RSQ(xm + yp);
    float r6 = RSQ(xp + y0), r7 = RSQ(xp + ym), r8 = RSQ(xp + yp);
    return (((r0 + r1) + (r2 + r3)) + ((r4 + r5) + (r6 + r7))) + r8;
}

// Diagonal (i==j) fully masked (all 9 shifts), center d2 made safe.
__device__ __forceinline__ float pair9_masked(float dx, float dy, bool diag) {
    float x0 = dx * dx, y0 = dy * dy;
    float tx = x0 + 100.0f, ty = y0 + 100.0f;
    float xm = fmaf(20.0f, dx, tx),  xp = fmaf(-20.0f, dx, tx);
    float ym = fmaf(20.0f, dy, ty),  yp = fmaf(-20.0f, dy, ty);
    float d2c = diag ? 1.0f : (x0 + y0);
    float r0 = RSQ(d2c),     r1 = RSQ(x0 + ym), r2 = RSQ(x0 + yp);
    float r3 = RSQ(xm + y0), r4 = RSQ(xm + ym), r5 = RSQ(xm + yp);
    float r6 = RSQ(xp + y0), r7 = RSQ(xp + ym), r8 = RSQ(xp + yp);
    float s = (((r0 + r1) + (r2 + r3)) + ((r4 + r5) + (r6 + r7))) + r8;
    return diag ? 0.0f : s;
}

// Triangular 256x256 tiles, j-split by 4. Diagonal tiles masked, off-diag weight 2.
__global__ __launch_bounds__(BLOCK) void pe_kernel(const float* __restrict__ xy,
                                                   float* __restrict__ partial) {
    __shared__ float2 sj[JSUB];
    const int t = threadIdx.x;

    // decode triangular index (scalar loop, <=32 SALU iters once per block)
    int rem = blockIdx.x;
    int ib = 0;
    while (rem >= NB - ib) { rem -= NB - ib; ++ib; }
    const int jb = ib + rem;

    const int i = ib * ITILE + t;
    const float2 pi = ((const float2*)xy)[i];
    const float xi = pi.x, yi = pi.y;

    const int j0 = jb * ITILE + blockIdx.y * JSUB;
    if (t < JSUB) sj[t] = ((const float2*)xy)[j0 + t];
    __syncthreads();

    float accA = 0.0f, accB = 0.0f;   // two accumulators break the acc chain

    if (ib == jb) {
#pragma unroll 8
        for (int jj = 0; jj < JSUB; jj += 2) {
            float2 pa = sj[jj];
            float2 pb = sj[jj + 1];
            accA += pair9_masked(xi - pa.x, yi - pa.y, i == (j0 + jj));
            accB += pair9_masked(xi - pb.x, yi - pb.y, i == (j0 + jj + 1));
        }
    } else {
#pragma unroll 8
        for (int jj = 0; jj < JSUB; jj += 2) {
            float2 pa = sj[jj];
            float2 pb = sj[jj + 1];
            accA += pair9(xi - pa.x, yi - pa.y);
            accB += pair9(xi - pb.x, yi - pb.y);
        }
        accA += accA;   // weight 2: mirrored (j,i) tile (shift set self-negating)
        accB += accB;
    }

    float acc = accA + accB;

    // wave-level reduction (deterministic), then combine 4 wave sums via LDS
    for (int off = 32; off > 0; off >>= 1)
        acc += __shfl_down(acc, off, 64);

    __shared__ float wsum[BLOCK / 64];
    if ((t & 63) == 0) wsum[t >> 6] = acc;
    __syncthreads();
    if (t == 0)
        partial[blockIdx.y * NTRI + blockIdx.x] =
            (wsum[0] + wsum[1]) + (wsum[2] + wsum[3]);
}

// Finisher: reduce NPART block partials + kinetic energy, write scalar.
__global__ __launch_bounds__(1024) void finish_kernel(const float* __restrict__ partial,
                                                      const float* __restrict__ pxy,
                                                      float* __restrict__ out) {
    const int t = threadIdx.x;
    float acc = 0.0f;
    for (int k = t; k < NPART; k += 1024) acc += partial[k];
    for (int k = t; k < 2 * N; k += 1024) {   // KE = sum p^2 / 2
        float p = pxy[k];
        acc += 0.5f * p * p;
    }
    __shared__ float red[1024];
    red[t] = acc;
    __syncthreads();
    for (int s = 512; s > 0; s >>= 1) {
        if (t < s) red[t] += red[t + s];
        __syncthreads();
    }
    if (t == 0) out[0] = red[0];
}

extern "C" void kernel_launch(void* const* d_in, const int* in_sizes, int n_in,
                              void* d_out, int out_size, void* d_ws, size_t ws_size,
                              hipStream_t stream) {
    const float* xy  = (const float*)d_in[0];
    const float* pxy = (const float*)d_in[1];
    float* out       = (float*)d_out;
    float* partial   = (float*)d_ws;   // NPART floats = 8448 B

    dim3 grid(NTRI, JSPLIT);
    pe_kernel<<<grid, BLOCK, 0, stream>>>(xy, partial);
    finish_kernel<<<1, 1024, 0, stream>>>(partial, pxy, out);
}

// Round 6
// 43.367 us; speedup vs baseline: 1.2128x; 1.0998x over previous
//
#include <hip/hip_runtime.h>

#define N 8192
#define BLOCK 256
#define ITILE 256                  // 256-wide i-tile, 1 i-point per thread
#define NB (N / ITILE)             // 32
#define NTRI (NB * (NB + 1) / 2)   // 528 triangular tiles
#define JSPLIT 4
#define JSUB (ITILE / JSPLIT)      // 64 j-points per block
#define NPART (NTRI * JSPLIT)      // 2112 partials

#define RSQ __builtin_amdgcn_rsqf

typedef float f32x2 __attribute__((ext_vector_type(2)));

// 9-image args for a packed j-pair: element-wise in the (jA, jB) packing, so all
// full-rate math selects to v_pk_{add,mul,fma}_f32 (VOP3P packed fp32, 2x rate).
// (dx±10)^2 = fma(±20, dx, dx^2+100); cross-shift d2s are sums of x-terms+y-terms.
__device__ __forceinline__ f32x2 pair9v(f32x2 dx, f32x2 dy) {
    f32x2 x0 = dx * dx, y0 = dy * dy;
    f32x2 tx = x0 + 100.0f, ty = y0 + 100.0f;
    f32x2 xm = __builtin_elementwise_fma((f32x2)(20.0f), dx, tx);
    f32x2 xp = __builtin_elementwise_fma((f32x2)(-20.0f), dx, tx);
    f32x2 ym = __builtin_elementwise_fma((f32x2)(20.0f), dy, ty);
    f32x2 yp = __builtin_elementwise_fma((f32x2)(-20.0f), dy, ty);
    f32x2 a0 = x0 + y0, a1 = x0 + ym, a2 = x0 + yp;
    f32x2 a3 = xm + y0, a4 = xm + ym, a5 = xm + yp;
    f32x2 a6 = xp + y0, a7 = xp + ym, a8 = xp + yp;
    f32x2 r0 = {RSQ(a0.x), RSQ(a0.y)};
    f32x2 r1 = {RSQ(a1.x), RSQ(a1.y)};
    f32x2 r2 = {RSQ(a2.x), RSQ(a2.y)};
    f32x2 r3 = {RSQ(a3.x), RSQ(a3.y)};
    f32x2 r4 = {RSQ(a4.x), RSQ(a4.y)};
    f32x2 r5 = {RSQ(a5.x), RSQ(a5.y)};
    f32x2 r6 = {RSQ(a6.x), RSQ(a6.y)};
    f32x2 r7 = {RSQ(a7.x), RSQ(a7.y)};
    f32x2 r8 = {RSQ(a8.x), RSQ(a8.y)};
    return (((r0 + r1) + (r2 + r3)) + ((r4 + r5) + (r6 + r7))) + r8;
}

// Diagonal-safe variant: i==j masked for ALL 9 shifts (center arg made safe, whole
// contribution zeroed), matching the reference's eye-mask-per-shift semantics.
__device__ __forceinline__ f32x2 pair9v_masked(f32x2 dx, f32x2 dy, bool dA, bool dB) {
    f32x2 x0 = dx * dx, y0 = dy * dy;
    f32x2 tx = x0 + 100.0f, ty = y0 + 100.0f;
    f32x2 xm = __builtin_elementwise_fma((f32x2)(20.0f), dx, tx);
    f32x2 xp = __builtin_elementwise_fma((f32x2)(-20.0f), dx, tx);
    f32x2 ym = __builtin_elementwise_fma((f32x2)(20.0f), dy, ty);
    f32x2 yp = __builtin_elementwise_fma((f32x2)(-20.0f), dy, ty);
    f32x2 a0 = x0 + y0, a1 = x0 + ym, a2 = x0 + yp;
    f32x2 a3 = xm + y0, a4 = xm + ym, a5 = xm + yp;
    f32x2 a6 = xp + y0, a7 = xp + ym, a8 = xp + yp;
    if (dA) a0.x = 1.0f;
    if (dB) a0.y = 1.0f;
    f32x2 r0 = {RSQ(a0.x), RSQ(a0.y)};
    f32x2 r1 = {RSQ(a1.x), RSQ(a1.y)};
    f32x2 r2 = {RSQ(a2.x), RSQ(a2.y)};
    f32x2 r3 = {RSQ(a3.x), RSQ(a3.y)};
    f32x2 r4 = {RSQ(a4.x), RSQ(a4.y)};
    f32x2 r5 = {RSQ(a5.x), RSQ(a5.y)};
    f32x2 r6 = {RSQ(a6.x), RSQ(a6.y)};
    f32x2 r7 = {RSQ(a7.x), RSQ(a7.y)};
    f32x2 r8 = {RSQ(a8.x), RSQ(a8.y)};
    f32x2 s = (((r0 + r1) + (r2 + r3)) + ((r4 + r5) + (r6 + r7))) + r8;
    if (dA) s.x = 0.0f;
    if (dB) s.y = 0.0f;
    return s;
}

// Triangular 256x256 tiles, j-split by 4; 2 j-points per inner iteration (packed).
__global__ __launch_bounds__(BLOCK) void pe_kernel(const float* __restrict__ xy,
                                                   float* __restrict__ partial) {
    __shared__ float sx[JSUB];
    __shared__ float sy[JSUB];
    const int t = threadIdx.x;

    // decode triangular index (scalar loop, <=32 SALU iters once per block)
    int rem = blockIdx.x;
    int ib = 0;
    while (rem >= NB - ib) { rem -= NB - ib; ++ib; }
    const int jb = ib + rem;

    const int i = ib * ITILE + t;
    const float2 pi = ((const float2*)xy)[i];
    const f32x2 xiv = {pi.x, pi.x};
    const f32x2 yiv = {pi.y, pi.y};

    const int j0 = jb * ITILE + blockIdx.y * JSUB;
    if (t < JSUB) {
        float2 pj = ((const float2*)xy)[j0 + t];
        sx[t] = pj.x;
        sy[t] = pj.y;
    }
    __syncthreads();

    const f32x2* sxv = (const f32x2*)sx;   // ds_read_b64 broadcast, conflict-free
    const f32x2* syv = (const f32x2*)sy;

    f32x2 acc = {0.0f, 0.0f};

    if (ib == jb) {
#pragma unroll 4
        for (int q = 0; q < JSUB / 2; ++q) {
            f32x2 dx = xiv - sxv[q];
            f32x2 dy = yiv - syv[q];
            int j = j0 + 2 * q;
            acc += pair9v_masked(dx, dy, i == j, i == j + 1);
        }
    } else {
#pragma unroll 4
        for (int q = 0; q < JSUB / 2; ++q) {
            f32x2 dx = xiv - sxv[q];
            f32x2 dy = yiv - syv[q];
            acc += pair9v(dx, dy);
        }
        acc += acc;   // weight 2: mirrored (j,i) tile (shift set self-negating)
    }

    float a = acc.x + acc.y;

    // wave-level reduction (deterministic), then combine 4 wave sums via LDS
    for (int off = 32; off > 0; off >>= 1)
        a += __shfl_down(a, off, 64);

    __shared__ float wsum[BLOCK / 64];
    if ((t & 63) == 0) wsum[t >> 6] = a;
    __syncthreads();
    if (t == 0)
        partial[blockIdx.y * NTRI + blockIdx.x] =
            (wsum[0] + wsum[1]) + (wsum[2] + wsum[3]);
}

// Finisher: reduce NPART block partials + kinetic energy, write scalar.
__global__ __launch_bounds__(1024) void finish_kernel(const float* __restrict__ partial,
                                                      const float* __restrict__ pxy,
                                                      float* __restrict__ out) {
    const int t = threadIdx.x;
    float acc = 0.0f;
    for (int k = t; k < NPART; k += 1024) acc += partial[k];
    for (int k = t; k < 2 * N; k += 1024) {   // KE = sum p^2 / 2
        float p = pxy[k];
        acc += 0.5f * p * p;
    }
    __shared__ float red[1024];
    red[t] = acc;
    __syncthreads();
    for (int s = 512; s > 0; s >>= 1) {
        if (t < s) red[t] += red[t + s];
        __syncthreads();
    }
    if (t == 0) out[0] = red[0];
}

extern "C" void kernel_launch(void* const* d_in, const int* in_sizes, int n_in,
                              void* d_out, int out_size, void* d_ws, size_t ws_size,
                              hipStream_t stream) {
    const float* xy  = (const float*)d_in[0];
    const float* pxy = (const float*)d_in[1];
    float* out       = (float*)d_out;
    float* partial   = (float*)d_ws;   // NPART floats = 8448 B

    dim3 grid(NTRI, JSPLIT);
    pe_kernel<<<grid, BLOCK, 0, stream>>>(xy, partial);
    finish_kernel<<<1, 1024, 0, stream>>>(partial, pxy, out);
}